// Round 5
// baseline (752.810 us; speedup 1.0000x reference)
//
#include <hip/hip_runtime.h>

// SSIM loss — row-streaming kernel. 96 planes of 512x512, split into
// 32-row horizontal bands: 1536 blocks x 512 threads (1 thread = 1 column).
//
// Per step (one input row): cooperative stage of {s=x+y, d=x-y} into a
// double-buffered 522-wide LDS row (1 barrier), per-thread 11-tap
// horizontal conv (computed ONCE per input row -- the R1-R4 structure
// recomputed it 3.5x across row strips), result pushed into an 11-deep
// per-thread register window (slot = j%11, static via 11-step frames),
// then an 11-tap vertical dot + SSIM for one output row.
// Per-thread live state ~44 window floats + ~30 working -> fits
// registers by construction instead of fighting the allocator.

typedef float v2f __attribute__((ext_vector_type(2)));

#define IMG 512
#define BH 32               // output rows per band
#define BUFW 522            // 512 + 2*5 halo
#define NPIX 25165824.0     // 32*3*512*512
#define C1f 1e-4f
#define C2f 9e-4f

// Gaussian(sigma=1.5, 11 taps), normalized fp32 (absmax 0.0 in R1-R4)
#define W0  0.00102838f
#define W1  0.00759876f
#define W2  0.03600077f
#define W3  0.10936068f
#define W4  0.21300552f
#define W5  0.26601173f
#define W6  0.21300552f
#define W7  0.10936068f
#define W8  0.03600077f
#define W9  0.00759876f
#define W10 0.00102838f

// One streamed row. S = j%11 (static within the 11-step frame).
// a0..a10 = slots (S+1+k)%11 holding h-rows j-10..j for the v-dot.
// Order within step: prefetch next input row (global, before barrier),
// barrier (orders prev step's reads vs this step's write AND prev
// step's write vs this step's reads), ds_write row j+1, ds_read row j.
#define STEP(S, a0,a1,a2,a3,a4,a5,a6,a7,a8,a9,a10) { \
    const int j = jj * 11 + (S); \
    float px = 0.f, py = 0.f; \
    { const int gr = by + j - 4;             /* input row j+1 */ \
      if ((unsigned)gr < (unsigned)IMG) { \
          const int gi = (gr << 9) + c; px = cp[gi]; py = ap[gi]; } } \
    __syncthreads(); \
    (((S) & 1) ? q0 : q1)[c + 5] = (v2f){px + py, px - py}; \
    { const v2f* rb = ((S) & 1) ? q1 : q0; \
      v2f t, hA, hB; \
      t = rb[c+0];  hA  = W0*t;  hB  = W0*(t*t); \
      t = rb[c+1];  hA += W1*t;  hB += W1*(t*t); \
      t = rb[c+2];  hA += W2*t;  hB += W2*(t*t); \
      t = rb[c+3];  hA += W3*t;  hB += W3*(t*t); \
      t = rb[c+4];  hA += W4*t;  hB += W4*(t*t); \
      t = rb[c+5];  hA += W5*t;  hB += W5*(t*t); \
      t = rb[c+6];  hA += W6*t;  hB += W6*(t*t); \
      t = rb[c+7];  hA += W7*t;  hB += W7*(t*t); \
      t = rb[c+8];  hA += W8*t;  hB += W8*(t*t); \
      t = rb[c+9];  hA += W9*t;  hB += W9*(t*t); \
      t = rb[c+10]; hA += W10*t; hB += W10*(t*t); \
      wA##S = hA; wB##S = hB; } \
    if (j >= 10 && j < 10 + BH) { \
      v2f vA = W0*wA##a0 + W1*wA##a1 + W2*wA##a2 + W3*wA##a3 + W4*wA##a4 \
             + W5*wA##a5 + W6*wA##a6 + W7*wA##a7 + W8*wA##a8 + W9*wA##a9 \
             + W10*wA##a10; \
      v2f vB = W0*wB##a0 + W1*wB##a1 + W2*wB##a2 + W3*wB##a3 + W4*wB##a4 \
             + W5*wB##a5 + W6*wB##a6 + W7*wB##a7 + W8*wB##a8 + W9*wB##a9 \
             + W10*wB##a10; \
      const float U = vA.x * vA.x, V = vA.y * vA.y; \
      const float hUmV = 0.5f * (U - V); \
      const float hUpV = 0.5f * (U + V); \
      const float n1 = hUmV + C1f; \
      const float n2 = 0.5f * (vB.x - vB.y) - hUmV + C2f; \
      const float d1 = hUpV + C1f; \
      const float d2 = 0.5f * (vB.x + vB.y) - hUpV + C2f; \
      lsum += (n1 * n2) * __builtin_amdgcn_rcpf(d1 * d2); } }

__global__ __launch_bounds__(512)
__attribute__((amdgpu_waves_per_eu(4, 4)))
void ssim_main(const float* __restrict__ clean,
               const float* __restrict__ adv,
               double* __restrict__ accum)
{
    __shared__ __align__(16) v2f buf0[BUFW];
    __shared__ __align__(16) v2f buf1[BUFW];
    __shared__ float wpart[8];

    const int c = threadIdx.x;          // column 0..511
    const int b = blockIdx.x;
    const int plane = b >> 4;           // 16 bands per plane
    const int by = (b & 15) * BH;       // band's first output row

    const float* __restrict__ cp = clean + (size_t)plane * (IMG * IMG);
    const float* __restrict__ ap = adv   + (size_t)plane * (IMG * IMG);

    // zero halo columns once (never rewritten; interior writes hit 5..516)
    if (c < 10) {
        const int hi = (c < 5) ? c : (512 + c);
        buf0[hi] = (v2f){0.f, 0.f};
        buf1[hi] = (v2f){0.f, 0.f};
    }

    v2f* q0 = buf0;                     // frame-even rows
    v2f* q1 = buf1;                     // frame-odd rows

    // prologue: stage input row m=0 (gr = by-5) into q0
    {
        const int gr = by - 5;
        float x = 0.f, y = 0.f;
        if ((unsigned)gr < (unsigned)IMG) {
            const int gi = (gr << 9) + c;
            x = cp[gi]; y = ap[gi];
        }
        q0[c + 5] = (v2f){x + y, x - y};
    }

    // 11-slot rolling window of horizontal-conv results
    v2f wA0={0.f,0.f}, wA1={0.f,0.f}, wA2={0.f,0.f}, wA3={0.f,0.f};
    v2f wA4={0.f,0.f}, wA5={0.f,0.f}, wA6={0.f,0.f}, wA7={0.f,0.f};
    v2f wA8={0.f,0.f}, wA9={0.f,0.f}, wA10={0.f,0.f};
    v2f wB0={0.f,0.f}, wB1={0.f,0.f}, wB2={0.f,0.f}, wB3={0.f,0.f};
    v2f wB4={0.f,0.f}, wB5={0.f,0.f}, wB6={0.f,0.f}, wB7={0.f,0.f};
    v2f wB8={0.f,0.f}, wB9={0.f,0.f}, wB10={0.f,0.f};

    float lsum = 0.f;

    // 4 frames x 11 steps = rows j=0..43; outputs at j in [10,42)
    for (int jj = 0; jj < 4; ++jj) {
        STEP(0,  1,2,3,4,5,6,7,8,9,10,0)
        STEP(1,  2,3,4,5,6,7,8,9,10,0,1)
        STEP(2,  3,4,5,6,7,8,9,10,0,1,2)
        STEP(3,  4,5,6,7,8,9,10,0,1,2,3)
        STEP(4,  5,6,7,8,9,10,0,1,2,3,4)
        STEP(5,  6,7,8,9,10,0,1,2,3,4,5)
        STEP(6,  7,8,9,10,0,1,2,3,4,5,6)
        STEP(7,  8,9,10,0,1,2,3,4,5,6,7)
        STEP(8,  9,10,0,1,2,3,4,5,6,7,8)
        STEP(9,  10,0,1,2,3,4,5,6,7,8,9)
        STEP(10, 0,1,2,3,4,5,6,7,8,9,10)
        v2f* tq = q0; q0 = q1; q1 = tq;   // 11 odd -> parity flips per frame
    }

    // ---- Reduce: wave shuffle -> LDS -> one atomic per block ----
    #pragma unroll
    for (int off = 32; off > 0; off >>= 1)
        lsum += __shfl_down(lsum, off);
    const int lane = c & 63;
    const int wave = c >> 6;            // 0..7
    if (lane == 0) wpart[wave] = lsum;
    __syncthreads();
    if (c == 0) {
        float bs = 0.f;
        #pragma unroll
        for (int w = 0; w < 8; ++w) bs += wpart[w];
        atomicAdd(accum, (double)bs);
    }
}

__global__ void ssim_finalize(const double* __restrict__ accum,
                              float* __restrict__ out)
{
    if (threadIdx.x == 0) {
        out[0] = 1.f - (float)(accum[0] / NPIX);
    }
}

extern "C" void kernel_launch(void* const* d_in, const int* in_sizes, int n_in,
                              void* d_out, int out_size, void* d_ws, size_t ws_size,
                              hipStream_t stream)
{
    const float* clean = (const float*)d_in[0];
    const float* adv   = (const float*)d_in[1];
    float* out = (float*)d_out;
    double* accum = (double*)d_ws;

    hipMemsetAsync(accum, 0, sizeof(double), stream);

    const int nblocks = 96 * 16;   // 96 planes * 16 bands of 32 rows
    ssim_main<<<nblocks, 512, 0, stream>>>(clean, adv, accum);
    ssim_finalize<<<1, 64, 0, stream>>>(accum, out);
}